// Round 3
// baseline (311.879 us; speedup 1.0000x reference)
//
#include <hip/hip_runtime.h>

#define K_CODES 1024
#define DIM 256
#define B_ 32
#define H_ 32
#define W_ 32
#define N_TOT (B_*H_*W_)   // 32768

// Exact replica of numpy's FLOAT_pairwise_sum for a 128-element contiguous
// block of already-rounded fp32 products p[d] = fl(v[d]*v[d]):
//   r[j] = sum_i p[8i+j] (sequential, 16 terms), then
//   ((r0+r1)+(r2+r3)) + ((r4+r5)+(r6+r7))
// All adds via __fadd_rn to forbid contraction/reassociation.
__device__ __forceinline__ float np_pw128_sq(const float* __restrict__ v) {
    float r[8];
    #pragma unroll
    for (int j = 0; j < 8; ++j) r[j] = __fmul_rn(v[j], v[j]);
    #pragma unroll
    for (int i = 1; i < 16; ++i)
        #pragma unroll
        for (int j = 0; j < 8; ++j)
            r[j] = __fadd_rn(r[j], __fmul_rn(v[8*i+j], v[8*i+j]));
    const float t01 = __fadd_rn(r[0], r[1]);
    const float t23 = __fadd_rn(r[2], r[3]);
    const float t45 = __fadd_rn(r[4], r[5]);
    const float t67 = __fadd_rn(r[6], r[7]);
    return __fadd_rn(__fadd_rn(t01, t23), __fadd_rn(t45, t67));
}

// ---- wnorm: s_w[k] = numpy-pairwise fp32 sum of w_k^2 over 256 dims ----
__global__ void vq_wnorm_kernel(const float* __restrict__ weight, float* __restrict__ wnorm) {
    int k = blockIdx.x * blockDim.x + threadIdx.x;
    if (k >= K_CODES) return;
    const float* wr = weight + (size_t)k * DIM;
    // n=256: pairwise splits 128+128
    wnorm[k] = __fadd_rn(np_pw128_sq(wr), np_pw128_sq(wr + 128));
}

#define ETS 260   // E tile stride (floats): 32 rows, +4 pad
#define WTS 68    // W tile stride (floats): 128 rows x 64 d, +4 pad

__global__ __launch_bounds__(256) void vq_main_kernel(
    const float* __restrict__ x, const float* __restrict__ weight,
    const float* __restrict__ wnorm,
    float* __restrict__ enc_out, float* __restrict__ qf_out,
    float* __restrict__ idx_out, float* __restrict__ q_out)
{
    __shared__ float E[32][ETS];       // 33280 B
    __shared__ float Wl[128][WTS];     // 34816 B
    __shared__ float wn[K_CODES];      //  4096 B
    __shared__ float rAcc[32][16];     //  2048 B  (numpy 8-accumulators, 2 blocks)
    __shared__ float sE[32];           //   128 B  (||e||^2, numpy-exact fp32)
    __shared__ int   r_k1[32];

    const int tid = threadIdx.x;
    const int blk = blockIdx.x;        // = b*32 + h
    const int b = blk >> 5;
    const int h = blk & 31;
    const long n0 = (long)blk * 32;    // row base; row w -> n0 + w

    for (int i = tid; i < K_CODES; i += 256) wn[i] = wnorm[i];

    // ---- Phase 1: x[b,c,h,w] -> E[w][c] (coalesced over w) ----
    {
        const int w  = tid & 31;
        const int c0 = tid >> 5;
        for (int c = c0; c < DIM; c += 8) {
            E[w][c] = x[(((long)b*DIM + c)*H_ + h)*W_ + w];
        }
    }
    __syncthreads();

    // ---- Phase 1b: write encoded_flat (float4 coalesced) ----
    {
        const int rsub = tid >> 6;     // 0..3
        const int c4   = tid & 63;     // float4 index
        #pragma unroll
        for (int r = 0; r < 32; r += 4) {
            const int row = r + rsub;
            const float4 v = *(const float4*)&E[row][c4*4];
            *(float4*)&enc_out[(n0 + row)*DIM + c4*4] = v;
        }
    }

    // ---- Phase 1c: s_e[row] = numpy-pairwise fp32 sum of e^2 (bit-exact) ----
    {
        const int r = tid >> 3;        // row 0..31
        const int a = tid & 7;         // accumulator lane 0..7
        float s0 = __fmul_rn(E[r][a], E[r][a]);
        float s1 = __fmul_rn(E[r][128 + a], E[r][128 + a]);
        #pragma unroll
        for (int i = 1; i < 16; ++i) {
            const float e0 = E[r][8*i + a];
            const float e1 = E[r][128 + 8*i + a];
            s0 = __fadd_rn(s0, __fmul_rn(e0, e0));
            s1 = __fadd_rn(s1, __fmul_rn(e1, e1));
        }
        rAcc[r][a]     = s0;
        rAcc[r][8 + a] = s1;
    }
    __syncthreads();
    if (tid < 32) {
        const float* r0 = rAcc[tid];
        const float b0 = __fadd_rn(__fadd_rn(__fadd_rn(r0[0], r0[1]), __fadd_rn(r0[2], r0[3])),
                                   __fadd_rn(__fadd_rn(r0[4], r0[5]), __fadd_rn(r0[6], r0[7])));
        const float b1 = __fadd_rn(__fadd_rn(__fadd_rn(r0[8], r0[9]), __fadd_rn(r0[10], r0[11])),
                                   __fadd_rn(__fadd_rn(r0[12], r0[13]), __fadd_rn(r0[14], r0[15])));
        sE[tid] = __fadd_rn(b0, b1);
    }
    __syncthreads();

    // ---- Phase 2: fp32 GEMM (sequential-FMA over d, matching sgemm) + argmin fold ----
    const int ti = tid >> 5;   // 0..7  -> rows ti*4 .. ti*4+3
    const int tj = tid & 31;   // 0..31 -> ks  kc + tj + 32*j

    float b1v[4]; int b1k[4];
    #pragma unroll
    for (int i = 0; i < 4; ++i) { b1v[i] = 3.4e38f; b1k[i] = 0x7fffffff; }

    for (int kc = 0; kc < K_CODES; kc += 128) {
        float acc[4][4];
        #pragma unroll
        for (int i = 0; i < 4; ++i)
            #pragma unroll
            for (int j = 0; j < 4; ++j) acc[i][j] = 0.f;

        for (int dsb = 0; dsb < 4; ++dsb) {    // d-subchunks of 64
            __syncthreads();                    // previous Wl fully consumed
            #pragma unroll
            for (int it = 0; it < 8; ++it) {    // stage W chunk [128][64]
                const int flat = it*256 + tid;
                const int kk = flat >> 4, dq = flat & 15;
                const float4 v = *(const float4*)&weight[((long)(kc+kk))*DIM + dsb*64 + dq*4];
                *(float4*)&Wl[kk][dq*4] = v;
            }
            __syncthreads();
            #pragma unroll 4
            for (int d4 = 0; d4 < 16; ++d4) {   // d ascending: dsb*64 + d4*4 + {0,1,2,3}
                float4 ev[4], wv[4];
                #pragma unroll
                for (int i = 0; i < 4; ++i) ev[i] = *(const float4*)&E[ti*4+i][dsb*64 + d4*4];
                #pragma unroll
                for (int j = 0; j < 4; ++j) wv[j] = *(const float4*)&Wl[tj + 32*j][d4*4];
                #pragma unroll
                for (int i = 0; i < 4; ++i)
                    #pragma unroll
                    for (int j = 0; j < 4; ++j) {
                        acc[i][j] = __fmaf_rn(ev[i].x, wv[j].x, acc[i][j]);
                        acc[i][j] = __fmaf_rn(ev[i].y, wv[j].y, acc[i][j]);
                        acc[i][j] = __fmaf_rn(ev[i].z, wv[j].z, acc[i][j]);
                        acc[i][j] = __fmaf_rn(ev[i].w, wv[j].w, acc[i][j]);
                    }
            }
        }
        // fold: q = fl(fl(s_e - fl(2*dot)) + s_w), first-min-index (numpy argmin)
        #pragma unroll
        for (int j = 0; j < 4; ++j) {
            const int k = kc + tj + 32*j;      // ascending per lane across kc,j
            const float wnk = wn[k];
            #pragma unroll
            for (int i = 0; i < 4; ++i) {
                const float twod = __fmul_rn(2.0f, acc[i][j]);       // exact
                const float t1   = __fadd_rn(sE[ti*4+i], -twod);     // fl(s_e - 2dot)
                const float v    = __fadd_rn(t1, wnk);               // fl(.. + s_w)
                if (v < b1v[i] || (v == b1v[i] && k < b1k[i])) { b1v[i] = v; b1k[i] = k; }
            }
        }
    }

    // ---- Phase 3: cross-lane lexicographic (v, k) min -> numpy first-min argmin ----
    #pragma unroll
    for (int i = 0; i < 4; ++i) {
        float v1 = b1v[i]; int k1 = b1k[i];
        #pragma unroll
        for (int m = 16; m >= 1; m >>= 1) {
            const float ov = __shfl_xor(v1, m);
            const int   ok = __shfl_xor(k1, m);
            if (ov < v1 || (ov == v1 && ok < k1)) { v1 = ov; k1 = ok; }
        }
        if (tj == 0) {
            const int row = ti*4 + i;
            r_k1[row] = k1;
            idx_out[n0 + row] = (float)k1;
        }
    }
    __syncthreads();

    // ---- Phase 4: gather codes -> quantized_flat (+ stash in E) ----
    {
        const int rsub = tid >> 6;
        const int c4   = tid & 63;
        #pragma unroll
        for (int r = 0; r < 32; r += 4) {
            const int row = r + rsub;
            const int k = r_k1[row];
            const float4 v = *(const float4*)&weight[(size_t)k*DIM + c4*4];
            *(float4*)&qf_out[(n0 + row)*DIM + c4*4] = v;
            *(float4*)&E[row][c4*4] = v;
        }
    }
    __syncthreads();

    // ---- Phase 5: scatter to NCHW quantized (coalesced over w) ----
    {
        const int w  = tid & 31;
        const int c0 = tid >> 5;
        for (int c = c0; c < DIM; c += 8) {
            q_out[(((long)b*DIM + c)*H_ + h)*W_ + w] = E[w][c];
        }
    }
}

extern "C" void kernel_launch(void* const* d_in, const int* in_sizes, int n_in,
                              void* d_out, int out_size, void* d_ws, size_t ws_size,
                              hipStream_t stream)
{
    const float* x      = (const float*)d_in[0];   // [32,256,32,32]
    const float* weight = (const float*)d_in[1];   // [1024,256]

    float* out = (float*)d_out;
    float* enc = out;                                   // [32768,256]
    float* qf  = enc + (size_t)N_TOT * DIM;             // [32768,256]
    float* idx = qf  + (size_t)N_TOT * DIM;             // [32768] (written as float)
    float* qo  = idx + N_TOT;                           // [32,256,32,32]

    float* wnorm = (float*)d_ws;                        // 1024 floats scratch

    vq_wnorm_kernel<<<K_CODES/256, 256, 0, stream>>>(weight, wnorm);
    vq_main_kernel<<<N_TOT/32, 256, 0, stream>>>(x, weight, wnorm, enc, qf, idx, qo);
}

// Round 5
// 172.408 us; speedup vs baseline: 1.8090x; 1.8090x over previous
//
#include <hip/hip_runtime.h>

#define K_CODES 1024
#define DIM 256
#define N_TOT 32768

typedef _Float16 f16;
typedef _Float16 f16x8 __attribute__((ext_vector_type(8)));
typedef _Float16 f16x4 __attribute__((ext_vector_type(4)));
typedef float f32x4 __attribute__((ext_vector_type(4)));

// Exact replica of numpy FLOAT_pairwise_sum for 128 contiguous squares (validated r3).
__device__ __forceinline__ float np_pw128_sq(const float* __restrict__ v) {
    float r[8];
    #pragma unroll
    for (int j = 0; j < 8; ++j) r[j] = __fmul_rn(v[j], v[j]);
    #pragma unroll
    for (int i = 1; i < 16; ++i)
        #pragma unroll
        for (int j = 0; j < 8; ++j)
            r[j] = __fadd_rn(r[j], __fmul_rn(v[8*i+j], v[8*i+j]));
    const float t01 = __fadd_rn(r[0], r[1]);
    const float t23 = __fadd_rn(r[2], r[3]);
    const float t45 = __fadd_rn(r[4], r[5]);
    const float t67 = __fadd_rn(r[6], r[7]);
    return __fadd_rn(__fadd_rn(t01, t23), __fadd_rn(t45, t67));
}

__global__ void vq_wnorm_kernel(const float* __restrict__ weight, float* __restrict__ wnorm) {
    int k = blockIdx.x * blockDim.x + threadIdx.x;
    if (k >= K_CODES) return;
    const float* wr = weight + (size_t)k * DIM;
    wnorm[k] = __fadd_rn(np_pw128_sq(wr), np_pw128_sq(wr + 128));
}

// W -> f16, scaled by 1024 (exact pow2) to avoid f16 denormals.
__global__ void vq_convw_kernel(const float* __restrict__ weight, f16* __restrict__ Wh) {
    const int k = blockIdx.x;          // 1024 blocks x 64 threads
    const int t = threadIdx.x;
    const float4 v = *(const float4*)&weight[(size_t)k * DIM + t * 4];
    f16x4 o;
    o[0] = (f16)(v.x * 1024.0f);
    o[1] = (f16)(v.y * 1024.0f);
    o[2] = (f16)(v.z * 1024.0f);
    o[3] = (f16)(v.w * 1024.0f);
    *(f16x4*)&Wh[(size_t)k * DIM + t * 4] = o;
}

template<bool PRE>
__global__ __launch_bounds__(512, 4) void vq_main_kernel(
    const float* __restrict__ x, const float* __restrict__ weight,
    const float* __restrict__ wnorm, const f16* __restrict__ Wh,
    float* __restrict__ enc_out, float* __restrict__ qf_out,
    float* __restrict__ idx_out, float* __restrict__ q_out)
{
    __shared__ __align__(16) f16 Eh[64][264];          // 33792 B, stride 528 B
    __shared__ __align__(16) char WlRaw[64 * 264 * 2]; // 33792 B: f16 Wl[64][264] | float F[32][260]
    __shared__ float wn[K_CODES];                      // 4096 B
    __shared__ float sE[64];
    __shared__ float rAcc[32][16];
    __shared__ unsigned rm[64];
    __shared__ unsigned long long rmEx[64];

    f16 (*Wl)[264] = (f16(*)[264])WlRaw;
    float (*F)[260] = (float(*)[260])WlRaw;

    const int tid = threadIdx.x;
    const int blk = blockIdx.x;        // 512 blocks: b = blk>>4, hp = blk&15
    const int b  = blk >> 4;
    const int hp = blk & 15;
    const long n0 = (long)blk * 64;    // global row base; local row = s*32 + w

    if (tid < 64) { rm[tid] = 0xFFFFFFFFu; rmEx[tid] = 0xFFFFFFFFFFFFFFFFull; }
    for (int i = tid; i < K_CODES; i += 512) wn[i] = wnorm[i];

    // ================= Phase 1: transpose, enc write, sE, f16 convert ==========
    for (int s = 0; s < 2; ++s) {
        const int h = hp * 2 + s;
        __syncthreads();                               // F free
        {
            const int w = tid & 31, c0 = tid >> 5;
            for (int c = c0; c < DIM; c += 16)
                F[w][c] = x[(((long)b * DIM + c) * 32 + h) * 32 + w];
        }
        __syncthreads();
        {   // encoded_flat write (float4 coalesced)
            const int c4 = tid & 63, rg = tid >> 6;
            #pragma unroll
            for (int r0 = 0; r0 < 32; r0 += 8) {
                const int row = r0 + rg;
                *(float4*)&enc_out[(n0 + s * 32 + row) * DIM + c4 * 4] =
                    *(const float4*)&F[row][c4 * 4];
            }
        }
        {   // numpy pairwise partials: 16 accumulators per row (2 blocks x 8)
            const int r = tid >> 4, half = (tid >> 3) & 1, a = tid & 7;
            const int base = half * 128 + a;
            float acc = __fmul_rn(F[r][base], F[r][base]);
            #pragma unroll
            for (int i = 1; i < 16; ++i) {
                const float e = F[r][base + 8 * i];
                acc = __fadd_rn(acc, __fmul_rn(e, e));
            }
            rAcc[r][half * 8 + a] = acc;
        }
        {   // f16 convert
            const int w = tid & 31, c0 = tid >> 5;
            for (int c = c0; c < DIM; c += 16)
                Eh[s * 32 + w][c] = (f16)F[w][c];
        }
        __syncthreads();
        if (tid < 32) {
            const float* r0 = rAcc[tid];
            const float b0 = __fadd_rn(__fadd_rn(__fadd_rn(r0[0], r0[1]), __fadd_rn(r0[2], r0[3])),
                                       __fadd_rn(__fadd_rn(r0[4], r0[5]), __fadd_rn(r0[6], r0[7])));
            const float b1 = __fadd_rn(__fadd_rn(__fadd_rn(r0[8], r0[9]), __fadd_rn(r0[10], r0[11])),
                                       __fadd_rn(__fadd_rn(r0[12], r0[13]), __fadd_rn(r0[14], r0[15])));
            sE[s * 32 + tid] = __fadd_rn(b0, b1);
        }
    }

    // ================= Phase 2: f16 MFMA distance pass =========================
    const int wid = tid >> 6, lane = tid & 63;
    const int mh = wid >> 2, qw = wid & 3;     // M-half (rows mh*32..), code-quarter of chunk
    const int fr = lane & 15, fg = lane >> 4;

    // A-fragments: 2 M-tiles x 8 K-steps, held in regs (64 VGPR)
    f16x8 afr[2][8];
    #pragma unroll
    for (int mt = 0; mt < 2; ++mt)
        #pragma unroll
        for (int kk = 0; kk < 8; ++kk)
            afr[mt][kk] = *(const f16x8*)&Eh[mh * 32 + mt * 16 + fr][kk * 32 + fg * 8];

    unsigned s1[8], s2[8];                     // per-slot top-2 packed (v_q<<10 | k)
    #pragma unroll
    for (int i = 0; i < 8; ++i) { s1[i] = 0xFFFFFFFFu; s2[i] = 0xFFFFFFFFu; }

    for (int ch = 0; ch < 16; ++ch) {          // 16 chunks of 64 codes
        __syncthreads();
        if (PRE) {
            #pragma unroll
            for (int u = 0; u < 4; ++u) {
                const int flat = u * 512 + tid;        // 0..2047 16B-units; 32 units/code row
                const int code = flat >> 5, seg = flat & 31;
                *(f16x8*)&Wl[code][seg * 8] =
                    *(const f16x8*)&Wh[((long)(ch * 64 + code)) * DIM + seg * 8];
            }
        } else {
            #pragma unroll
            for (int u = 0; u < 4; ++u) {
                const int flat = u * 512 + tid;
                const int code = flat >> 5, seg = flat & 31;
                const float4 v0 = *(const float4*)&weight[((long)(ch * 64 + code)) * DIM + seg * 8];
                const float4 v1 = *(const float4*)&weight[((long)(ch * 64 + code)) * DIM + seg * 8 + 4];
                f16x8 t;
                t[0] = (f16)(v0.x * 1024.0f); t[1] = (f16)(v0.y * 1024.0f);
                t[2] = (f16)(v0.z * 1024.0f); t[3] = (f16)(v0.w * 1024.0f);
                t[4] = (f16)(v1.x * 1024.0f); t[5] = (f16)(v1.y * 1024.0f);
                t[6] = (f16)(v1.z * 1024.0f); t[7] = (f16)(v1.w * 1024.0f);
                *(f16x8*)&Wl[code][seg * 8] = t;
            }
        }
        __syncthreads();

        f32x4 acc0 = {0.f, 0.f, 0.f, 0.f}, acc1 = {0.f, 0.f, 0.f, 0.f};
        #pragma unroll
        for (int kk = 0; kk < 8; ++kk) {
            const f16x8 bfr = *(const f16x8*)&Wl[qw * 16 + fr][kk * 32 + fg * 8];
            acc0 = __builtin_amdgcn_mfma_f32_16x16x32_f16(afr[0][kk], bfr, acc0, 0, 0, 0);
            acc1 = __builtin_amdgcn_mfma_f32_16x16x32_f16(afr[1][kk], bfr, acc1, 0, 0, 0);
        }

        const int code = ch * 64 + qw * 16 + fr;
        const float wnk = wn[code];
        #pragma unroll
        for (int q = 0; q < 4; ++q) {
            {   // M-tile 0: slot q
                const float vp = fmaf(acc0[q], -0.001953125f, wnk);   // wn - 2*dot (dot scaled /1024)
                const unsigned uq = (unsigned)fmaf(vp, 1048576.0f, 1048576.0f);
                const unsigned u = uq * 1024u + (unsigned)code;
                s2[q] = min(s2[q], max(s1[q], u));
                s1[q] = min(s1[q], u);
            }
            {   // M-tile 1: slot 4+q
                const float vp = fmaf(acc1[q], -0.001953125f, wnk);
                const unsigned uq = (unsigned)fmaf(vp, 1048576.0f, 1048576.0f);
                const unsigned u = uq * 1024u + (unsigned)code;
                s2[4 + q] = min(s2[4 + q], max(s1[4 + q], u));
                s1[4 + q] = min(s1[4 + q], u);
            }
        }
    }

    // approximate global min per row
    #pragma unroll
    for (int sl = 0; sl < 8; ++sl) {
        unsigned bmin = s1[sl];
        bmin = min(bmin, (unsigned)__shfl_xor((int)bmin, 1));
        bmin = min(bmin, (unsigned)__shfl_xor((int)bmin, 2));
        bmin = min(bmin, (unsigned)__shfl_xor((int)bmin, 4));
        bmin = min(bmin, (unsigned)__shfl_xor((int)bmin, 8));
        if (fr == 0) {
            const int row = mh * 32 + (sl >> 2) * 16 + fg * 4 + (sl & 3);
            atomicMin(&rm[row], bmin);
        }
    }
    __syncthreads();

    // ================= Phase 3: exact fp32 re-check (numpy-bit-exact, r3 recipe) ==
    #pragma unroll
    for (int sl = 0; sl < 8; ++sl) {
        const int row = mh * 32 + (sl >> 2) * 16 + fg * 4 + (sl & 3);
        const unsigned thr = (rm[row] >> 10) + 1000u;  // margin ~9.5e-4: ~60x f16-pass max error
        #pragma unroll
        for (int c = 0; c < 2; ++c) {
            const unsigned u = c ? s2[sl] : s1[sl];
            if ((u >> 10) <= thr) {
                const int k = (int)(u & 1023u);
                const float* ep = enc_out + (n0 + row) * DIM;
                const float* wp = weight + (long)k * DIM;
                float dot = 0.0f;
                for (int d4 = 0; d4 < 64; ++d4) {      // d strictly ascending
                    const float4 ev = *(const float4*)&ep[d4 * 4];
                    const float4 wv = *(const float4*)&wp[d4 * 4];
                    dot = __fmaf_rn(ev.x, wv.x, dot);
                    dot = __fmaf_rn(ev.y, wv.y, dot);
                    dot = __fmaf_rn(ev.z, wv.z, dot);
                    dot = __fmaf_rn(ev.w, wv.w, dot);
                }
                const float vex = __fadd_rn(__fadd_rn(sE[row], -__fmul_rn(2.0f, dot)), wn[k]);
                const unsigned long long pk =
                    (((unsigned long long)__float_as_uint(vex)) << 10) | (unsigned long long)k;
                atomicMin(&rmEx[row], pk);
            }
        }
    }
    __syncthreads();

    if (tid < 64) idx_out[n0 + tid] = (float)(unsigned)(rmEx[tid] & 1023ull);

    // ================= Phase 4/5: gather codes -> qf + NCHW scatter ============
    for (int s = 0; s < 2; ++s) {
        __syncthreads();                               // F (=Wl) free
        {
            const int c4 = tid & 63, rg = tid >> 6;
            #pragma unroll
            for (int r0 = 0; r0 < 32; r0 += 8) {
                const int row = r0 + rg;
                const int k = (int)(unsigned)(rmEx[s * 32 + row] & 1023ull);
                const float4 v = *(const float4*)&weight[(long)k * DIM + c4 * 4];
                *(float4*)&qf_out[(n0 + s * 32 + row) * DIM + c4 * 4] = v;
                *(float4*)&F[row][c4 * 4] = v;
            }
        }
        __syncthreads();
        {
            const int w = tid & 31, c0 = tid >> 5;
            const int h = hp * 2 + s;
            for (int c = c0; c < DIM; c += 16)
                q_out[(((long)b * DIM + c) * 32 + h) * 32 + w] = F[w][c];
        }
    }
}

extern "C" void kernel_launch(void* const* d_in, const int* in_sizes, int n_in,
                              void* d_out, int out_size, void* d_ws, size_t ws_size,
                              hipStream_t stream)
{
    const float* x      = (const float*)d_in[0];   // [32,256,32,32]
    const float* weight = (const float*)d_in[1];   // [1024,256]

    float* out = (float*)d_out;
    float* enc = out;                                   // [32768,256]
    float* qf  = enc + (size_t)N_TOT * DIM;             // [32768,256]
    float* idx = qf  + (size_t)N_TOT * DIM;             // [32768] as float
    float* qo  = idx + N_TOT;                           // [32,256,32,32]

    float* wnorm = (float*)d_ws;                        // 4 KB
    f16*   Wh    = (f16*)((char*)d_ws + 4096);          // 512 KB (if it fits)

    const bool pre = ws_size >= (size_t)(4096 + K_CODES * DIM * 2 + 64);

    vq_wnorm_kernel<<<K_CODES / 256, 256, 0, stream>>>(weight, wnorm);
    if (pre) {
        vq_convw_kernel<<<K_CODES, 64, 0, stream>>>(weight, Wh);
        vq_main_kernel<true><<<512, 512, 0, stream>>>(x, weight, wnorm, Wh, enc, qf, idx, qo);
    } else {
        vq_main_kernel<false><<<512, 512, 0, stream>>>(x, weight, wnorm, Wh, enc, qf, idx, qo);
    }
}